// Round 1
// baseline (466.153 us; speedup 1.0000x reference)
//
#include <hip/hip_runtime.h>

// Sizes are fixed by the problem.
#define S_HID 2048
#define S_SEQ 2048
#define S_B   2
#define S_NH  16
#define S_HD  128
#define S_M   (S_B * S_SEQ)   // 4096 rows
#define S_BH  (S_B * S_NH)    // 32

typedef __bf16 bf16_t;
typedef __bf16 bf16x8 __attribute__((ext_vector_type(8)));
typedef __bf16 bf16x4 __attribute__((ext_vector_type(4)));
typedef float  floatx4 __attribute__((ext_vector_type(4)));

typedef __attribute__((address_space(1))) unsigned int as1_uint;
typedef __attribute__((address_space(3))) unsigned int as3_uint;

// async global->LDS, 16B per lane; LDS dest = wave-uniform base + lane*16
__device__ __forceinline__ void gload_lds16(const void* g, void* l) {
    __builtin_amdgcn_global_load_lds((as1_uint*)g, (as3_uint*)l, 16, 0, 0);
}

// ---------------- fp32 -> bf16 convert ----------------
__global__ void cvt_bf16(const float* __restrict__ src, bf16_t* __restrict__ dst, int n) {
    int nv = n >> 2;
    int stride = gridDim.x * blockDim.x;
    for (int i = blockIdx.x * blockDim.x + threadIdx.x; i < nv; i += stride) {
        float4 v = ((const float4*)src)[i];
        bf16x4 o;
        o.x = (bf16_t)v.x; o.y = (bf16_t)v.y; o.z = (bf16_t)v.z; o.w = (bf16_t)v.w;
        ((bf16x4*)dst)[i] = o;
    }
}

// ---------------- V [bh][s][d] -> Vt [bh][d][s] ----------------
__global__ void transpose_v(const bf16_t* __restrict__ V, bf16_t* __restrict__ Vt) {
    __shared__ bf16_t tile[64 * 65];
    const int bh = blockIdx.z, s0 = blockIdx.y * 64, d0 = blockIdx.x * 64;
    const int t = threadIdx.x;
    #pragma unroll
    for (int i = 0; i < 16; ++i) {
        int idx = i * 256 + t;
        int r = idx >> 6, c = idx & 63;
        tile[r * 65 + c] = V[((size_t)bh * S_SEQ + s0 + r) * S_HD + d0 + c];
    }
    __syncthreads();
    #pragma unroll
    for (int i = 0; i < 16; ++i) {
        int idx = i * 256 + t;
        int rr = idx >> 6, cc = idx & 63;
        Vt[((size_t)bh * S_HD + d0 + rr) * S_SEQ + s0 + cc] = tile[cc * 65 + rr];
    }
}

// ---------------- bf16 GEMM: C = A[4096x2048] * W[2048x2048]^T + bias ----------------
// mode 0: out bf16 in [B,H,S,D] layout, value = (acc+bias)*scale   (QKV projections)
// mode 1: out fp32 row-major [M][N], value = acc+bias              (final projection)
__global__ __launch_bounds__(256, 2)
void gemm_bt(const bf16_t* __restrict__ A, const bf16_t* __restrict__ W,
             const float* __restrict__ bias, void* __restrict__ out,
             int mode, float scale) {
    __shared__ __align__(16) bf16_t ldsA[128 * 64];
    __shared__ __align__(16) bf16_t ldsB[128 * 64];
    const int tid = threadIdx.x;
    const int wid = tid >> 6, lane = tid & 63;
    const int m0 = blockIdx.y * 128, n0 = blockIdx.x * 128;
    const int wm = (wid & 1) * 64, wn = (wid >> 1) * 64;
    const int lm = lane & 15, quad = lane >> 4;
    const int srow = lane >> 3;   // row within 1KB slot (8 rows x 128B)
    const int scol = lane & 7;    // 16B chunk slot within row

    floatx4 acc[4][4];
    #pragma unroll
    for (int i = 0; i < 4; ++i)
        #pragma unroll
        for (int j = 0; j < 4; ++j)
            acc[i][j] = (floatx4){0.f, 0.f, 0.f, 0.f};

    for (int kt = 0; kt < S_HID; kt += 64) {
        // stage A-tile 128x64 and B-tile 128x64, XOR-swizzled chunks (bank-conflict-free reads)
        #pragma unroll
        for (int i = 0; i < 4; ++i) {
            int slot = i * 4 + wid;             // 0..15, wave-uniform
            int row = slot * 8 + srow;          // 0..127
            int cg = scol ^ (row & 7);          // source chunk for this LDS slot pos
            gload_lds16(A + (size_t)(m0 + row) * S_HID + kt + cg * 8, &ldsA[slot * 512]);
            gload_lds16(W + (size_t)(n0 + row) * S_HID + kt + cg * 8, &ldsB[slot * 512]);
        }
        __syncthreads();
        #pragma unroll
        for (int k2 = 0; k2 < 2; ++k2) {
            bf16x8 af[4], bfr[4];
            #pragma unroll
            for (int i = 0; i < 4; ++i) {
                int row = wm + i * 16 + lm;
                int cc = (k2 * 4 + quad) ^ (row & 7);
                af[i] = *(const bf16x8*)&ldsA[row * 64 + cc * 8];
            }
            #pragma unroll
            for (int j = 0; j < 4; ++j) {
                int row = wn + j * 16 + lm;
                int cc = (k2 * 4 + quad) ^ (row & 7);
                bfr[j] = *(const bf16x8*)&ldsB[row * 64 + cc * 8];
            }
            #pragma unroll
            for (int i = 0; i < 4; ++i)
                #pragma unroll
                for (int j = 0; j < 4; ++j)
                    acc[i][j] = __builtin_amdgcn_mfma_f32_16x16x32_bf16(af[i], bfr[j], acc[i][j], 0, 0, 0);
        }
        __syncthreads();
    }

    // epilogue: C/D layout col = lane&15, row = quad*4 + reg
    if (mode == 0) {
        bf16_t* Ob = (bf16_t*)out;
        #pragma unroll
        for (int i = 0; i < 4; ++i) {
            #pragma unroll
            for (int j = 0; j < 4; ++j) {
                int n = n0 + wn + j * 16 + lm;
                float bv = bias[n];
                int h = n >> 7, d = n & 127;
                #pragma unroll
                for (int r = 0; r < 4; ++r) {
                    int m = m0 + wm + i * 16 + quad * 4 + r;
                    int b = m >> 11, s = m & 2047;
                    Ob[(((size_t)(b * S_NH + h)) * S_SEQ + s) * S_HD + d] =
                        (bf16_t)((acc[i][j][r] + bv) * scale);
                }
            }
        }
    } else {
        float* Of = (float*)out;
        #pragma unroll
        for (int i = 0; i < 4; ++i) {
            #pragma unroll
            for (int j = 0; j < 4; ++j) {
                int n = n0 + wn + j * 16 + lm;
                float bv = bias[n];
                #pragma unroll
                for (int r = 0; r < 4; ++r) {
                    int m = m0 + wm + i * 16 + quad * 4 + r;
                    Of[(size_t)m * S_HID + n] = acc[i][j][r] + bv;
                }
            }
        }
    }
}

// ---------------- flash attention (causal) ----------------
// Q,K: [bh][s][d] bf16 (Q pre-scaled by 1/sqrt(d)*log2e); Vt: [bh][d][s] bf16
// O: [b][s][h*128+d] bf16. 64 q-rows per block (16 per wave), 128-key tiles.
__global__ __launch_bounds__(256, 2)
void attn(const bf16_t* __restrict__ Q, const bf16_t* __restrict__ K,
          const bf16_t* __restrict__ Vt, bf16_t* __restrict__ O) {
    __shared__ __align__(16) bf16_t ldsK[128 * 128];   // 32KB; first 16KB reused as P
    __shared__ __align__(16) bf16_t ldsV[128 * 128];   // 32KB
    const int tid = threadIdx.x, wid = tid >> 6, lane = tid & 63;
    const int lm = lane & 15, quad = lane >> 4;
    const int q0 = blockIdx.x * 64;
    const int bh = blockIdx.y;
    const int b = bh >> 4, h = bh & 15;

    // Q fragments (A-operand): A[m=lane&15][k=quad*8+j], 4 k-steps of 32 over d
    bf16x8 qf[4];
    {
        const bf16_t* qp = Q + ((size_t)bh * S_SEQ + q0 + wid * 16 + lm) * S_HD + quad * 8;
        #pragma unroll
        for (int ks = 0; ks < 4; ++ks) qf[ks] = *(const bf16x8*)(qp + ks * 32);
    }

    floatx4 oa[8];
    #pragma unroll
    for (int j = 0; j < 8; ++j) oa[j] = (floatx4){0.f, 0.f, 0.f, 0.f};
    float m_st[4] = {-1e30f, -1e30f, -1e30f, -1e30f};
    float l_st[4] = {0.f, 0.f, 0.f, 0.f};

    const int nkt = (q0 + 64 + 127) >> 7;
    for (int kti = 0; kti < nkt; ++kti) {
        const int kt = kti * 128;
        // stage K-tile [128 keys x 128 d] and Vt-tile [128 d x 128 keys], swizzled
        #pragma unroll
        for (int i = 0; i < 8; ++i) {
            int slot = i * 4 + wid;             // 0..31, wave-uniform
            int row = slot * 4 + quad;          // 0..127 (1KB = 4 rows x 256B)
            int cg = lm ^ (row & 7);
            gload_lds16(K + ((size_t)bh * S_SEQ + kt + row) * S_HD + cg * 8, &ldsK[slot * 512]);
            gload_lds16(Vt + ((size_t)bh * S_HD + row) * S_SEQ + kt + cg * 8, &ldsV[slot * 512]);
        }
        __syncthreads();

        // S = Q * K^T  (16 q-rows x 128 keys per wave)
        floatx4 sa[8];
        #pragma unroll
        for (int j = 0; j < 8; ++j) sa[j] = (floatx4){0.f, 0.f, 0.f, 0.f};
        #pragma unroll
        for (int ks = 0; ks < 4; ++ks) {
            #pragma unroll
            for (int j = 0; j < 8; ++j) {
                int row = j * 16 + lm;
                int cc = (ks * 4 + quad) ^ (row & 7);
                bf16x8 kb = *(const bf16x8*)&ldsK[row * 128 + cc * 8];
                sa[j] = __builtin_amdgcn_mfma_f32_16x16x32_bf16(qf[ks], kb, sa[j], 0, 0, 0);
            }
        }
        // causal mask, only the diagonal tile needs it
        if (kti == nkt - 1) {
            #pragma unroll
            for (int j = 0; j < 8; ++j)
                #pragma unroll
                for (int r = 0; r < 4; ++r) {
                    int key = kt + j * 16 + lm;
                    int qr = q0 + wid * 16 + quad * 4 + r;
                    if (key > qr) sa[j][r] = -1e30f;
                }
        }
        // online softmax (scores already in log2 units; Q carries 1/sqrt(d)*log2e)
        float al[4];
        #pragma unroll
        for (int r = 0; r < 4; ++r) {
            float v = sa[0][r];
            #pragma unroll
            for (int j = 1; j < 8; ++j) v = fmaxf(v, sa[j][r]);
            v = fmaxf(v, __shfl_xor(v, 1));
            v = fmaxf(v, __shfl_xor(v, 2));
            v = fmaxf(v, __shfl_xor(v, 4));
            v = fmaxf(v, __shfl_xor(v, 8));
            float mn = fmaxf(m_st[r], v);
            al[r] = exp2f(m_st[r] - mn);
            m_st[r] = mn;
        }
        __syncthreads();   // all waves done reading ldsK before P overwrites it
        bf16_t* pb = &ldsK[wid * 2048];   // per-wave 16x128 P region, swizzled
        float rs[4] = {0.f, 0.f, 0.f, 0.f};
        #pragma unroll
        for (int j = 0; j < 8; ++j)
            #pragma unroll
            for (int r = 0; r < 4; ++r) {
                float p = exp2f(sa[j][r] - m_st[r]);
                rs[r] += p;
                int mrow = quad * 4 + r;
                int col = j * 16 + lm;
                int ch = (col >> 3) ^ (mrow & 7);
                pb[mrow * 128 + ch * 8 + (col & 7)] = (bf16_t)p;
            }
        #pragma unroll
        for (int r = 0; r < 4; ++r) {
            float v = rs[r];
            v += __shfl_xor(v, 1);
            v += __shfl_xor(v, 2);
            v += __shfl_xor(v, 4);
            v += __shfl_xor(v, 8);
            l_st[r] = l_st[r] * al[r] + v;
        }
        #pragma unroll
        for (int j = 0; j < 8; ++j)
            #pragma unroll
            for (int r = 0; r < 4; ++r) oa[j][r] *= al[r];
        // O += P * V   (P via LDS round-trip into A-layout; same-wave DS ops are ordered)
        #pragma unroll
        for (int ks2 = 0; ks2 < 4; ++ks2) {
            int cc = (ks2 * 4 + quad) ^ (lm & 7);
            bf16x8 pa = *(const bf16x8*)&pb[lm * 128 + cc * 8];
            #pragma unroll
            for (int j2 = 0; j2 < 8; ++j2) {
                int vrow = j2 * 16 + lm;
                int vc = (ks2 * 4 + quad) ^ (vrow & 7);
                bf16x8 vb = *(const bf16x8*)&ldsV[vrow * 128 + vc * 8];
                oa[j2] = __builtin_amdgcn_mfma_f32_16x16x32_bf16(pa, vb, oa[j2], 0, 0, 0);
            }
        }
        __syncthreads();
    }

    // epilogue: O[b][q][h*128+d] bf16
    #pragma unroll
    for (int j2 = 0; j2 < 8; ++j2)
        #pragma unroll
        for (int r = 0; r < 4; ++r) {
            float o = oa[j2][r] / l_st[r];
            int qr = q0 + wid * 16 + quad * 4 + r;
            int col = h * S_HD + j2 * 16 + lm;
            O[((size_t)b * S_SEQ + qr) * S_HID + col] = (bf16_t)o;
        }
}

extern "C" void kernel_launch(void* const* d_in, const int* in_sizes, int n_in,
                              void* d_out, int out_size, void* d_ws, size_t ws_size,
                              hipStream_t stream) {
    const float* hs = (const float*)d_in[0];
    const float* qw = (const float*)d_in[1];
    const float* kw = (const float*)d_in[2];
    const float* vw = (const float*)d_in[3];
    const float* ow = (const float*)d_in[4];
    const float* qbias = (const float*)d_in[5];
    const float* kbias = (const float*)d_in[6];
    const float* vbias = (const float*)d_in[7];
    const float* obias = (const float*)d_in[8];

    char* ws = (char*)d_ws;
    bf16_t* Xb  = (bf16_t*)(ws + 0);           // 16 MB, reused as attention output
    bf16_t* Wqb = (bf16_t*)(ws + 16777216);    // 8 MB
    bf16_t* Wkb = (bf16_t*)(ws + 25165824);
    bf16_t* Wvb = (bf16_t*)(ws + 33554432);
    bf16_t* Wob = (bf16_t*)(ws + 41943040);
    bf16_t* Qb  = (bf16_t*)(ws + 50331648);    // 16 MB each
    bf16_t* Kb  = (bf16_t*)(ws + 67108864);
    bf16_t* Vb  = (bf16_t*)(ws + 83886080);
    bf16_t* Vtb = (bf16_t*)(ws + 100663296);
    bf16_t* Ob  = Xb;                          // X dead after QKV GEMMs

    cvt_bf16<<<1024, 256, 0, stream>>>(hs, Xb, S_M * S_HID);
    cvt_bf16<<<512, 256, 0, stream>>>(qw, Wqb, S_HID * S_HID);
    cvt_bf16<<<512, 256, 0, stream>>>(kw, Wkb, S_HID * S_HID);
    cvt_bf16<<<512, 256, 0, stream>>>(vw, Wvb, S_HID * S_HID);
    cvt_bf16<<<512, 256, 0, stream>>>(ow, Wob, S_HID * S_HID);

    dim3 gg(S_HID / 128, S_M / 128);  // (16, 32)
    // fold softmax scale 1/sqrt(128) and log2(e) into Q
    const float qscale = 0.08838834764831845f * 1.4426950408889634f;
    gemm_bt<<<gg, 256, 0, stream>>>(Xb, Wqb, qbias, (void*)Qb, 0, qscale);
    gemm_bt<<<gg, 256, 0, stream>>>(Xb, Wkb, kbias, (void*)Kb, 0, 1.0f);
    gemm_bt<<<gg, 256, 0, stream>>>(Xb, Wvb, vbias, (void*)Vb, 0, 1.0f);

    transpose_v<<<dim3(2, 32, 32), 256, 0, stream>>>(Vb, Vtb);

    attn<<<dim3(S_SEQ / 64, S_BH), 256, 0, stream>>>(Qb, Kb, Vtb, Ob);

    gemm_bt<<<gg, 256, 0, stream>>>(Ob, Wob, obias, d_out, 1, 1.0f);
}

// Round 2
// 417.543 us; speedup vs baseline: 1.1164x; 1.1164x over previous
//
#include <hip/hip_runtime.h>

// Sizes are fixed by the problem.
#define S_HID 2048
#define S_SEQ 2048
#define S_B   2
#define S_NH  16
#define S_HD  128
#define S_M   (S_B * S_SEQ)   // 4096 rows
#define S_BH  (S_B * S_NH)    // 32

typedef __bf16 bf16_t;
typedef __bf16 bf16x8 __attribute__((ext_vector_type(8)));
typedef __bf16 bf16x4 __attribute__((ext_vector_type(4)));
typedef float  floatx4 __attribute__((ext_vector_type(4)));

typedef __attribute__((address_space(1))) unsigned int as1_uint;
typedef __attribute__((address_space(3))) unsigned int as3_uint;

// async global->LDS, 16B per lane; LDS dest = wave-uniform base + lane*16
__device__ __forceinline__ void gload_lds16(const void* g, void* l) {
    __builtin_amdgcn_global_load_lds((as1_uint*)g, (as3_uint*)l, 16, 0, 0);
}

// ---------------- fp32 -> bf16 convert ----------------
__global__ void cvt_bf16(const float* __restrict__ src, bf16_t* __restrict__ dst, int n) {
    int nv = n >> 2;
    int stride = gridDim.x * blockDim.x;
    for (int i = blockIdx.x * blockDim.x + threadIdx.x; i < nv; i += stride) {
        float4 v = ((const float4*)src)[i];
        bf16x4 o;
        o.x = (bf16_t)v.x; o.y = (bf16_t)v.y; o.z = (bf16_t)v.z; o.w = (bf16_t)v.w;
        ((bf16x4*)dst)[i] = o;
    }
}

// ---------------- V [bh][s][d] -> Vt [bh][d][s] ----------------
__global__ void transpose_v(const bf16_t* __restrict__ V, bf16_t* __restrict__ Vt) {
    __shared__ bf16_t tile[64 * 65];
    const int bh = blockIdx.z, s0 = blockIdx.y * 64, d0 = blockIdx.x * 64;
    const int t = threadIdx.x;
    #pragma unroll
    for (int i = 0; i < 16; ++i) {
        int idx = i * 256 + t;
        int r = idx >> 6, c = idx & 63;
        tile[r * 65 + c] = V[((size_t)bh * S_SEQ + s0 + r) * S_HD + d0 + c];
    }
    __syncthreads();
    #pragma unroll
    for (int i = 0; i < 16; ++i) {
        int idx = i * 256 + t;
        int rr = idx >> 6, cc = idx & 63;
        Vt[((size_t)bh * S_HD + d0 + rr) * S_SEQ + s0 + cc] = tile[cc * 65 + rr];
    }
}

// ---------------- bf16 GEMM: C = A[4096x2048] * W[2048x2048]^T + bias ----------------
// mode 0: out bf16 in [B,H,S,D] layout, value = (acc+bias)*scale   (QKV projections)
// mode 1: out fp32 row-major [M][N], value = acc+bias              (final projection)
__global__ __launch_bounds__(256, 2)
void gemm_bt(const bf16_t* __restrict__ A, const bf16_t* __restrict__ W,
             const float* __restrict__ bias, void* __restrict__ out,
             int mode, float scale) {
    __shared__ __align__(16) bf16_t ldsA[128 * 64];
    __shared__ __align__(16) bf16_t ldsB[128 * 64];
    const int tid = threadIdx.x;
    const int wid = tid >> 6, lane = tid & 63;
    const int m0 = blockIdx.y * 128, n0 = blockIdx.x * 128;
    const int wm = (wid & 1) * 64, wn = (wid >> 1) * 64;
    const int lm = lane & 15, quad = lane >> 4;
    const int srow = lane >> 3;   // row within 1KB slot (8 rows x 128B)
    const int scol = lane & 7;    // 16B chunk slot within row

    floatx4 acc[4][4];
    #pragma unroll
    for (int i = 0; i < 4; ++i)
        #pragma unroll
        for (int j = 0; j < 4; ++j)
            acc[i][j] = (floatx4){0.f, 0.f, 0.f, 0.f};

    for (int kt = 0; kt < S_HID; kt += 64) {
        // stage A-tile 128x64 and B-tile 128x64, XOR-swizzled chunks (bank-conflict-free reads)
        #pragma unroll
        for (int i = 0; i < 4; ++i) {
            int slot = i * 4 + wid;             // 0..15, wave-uniform
            int row = slot * 8 + srow;          // 0..127
            int cg = scol ^ (row & 7);          // source chunk for this LDS slot pos
            gload_lds16(A + (size_t)(m0 + row) * S_HID + kt + cg * 8, &ldsA[slot * 512]);
            gload_lds16(W + (size_t)(n0 + row) * S_HID + kt + cg * 8, &ldsB[slot * 512]);
        }
        __syncthreads();
        #pragma unroll
        for (int k2 = 0; k2 < 2; ++k2) {
            bf16x8 af[4], bfr[4];
            #pragma unroll
            for (int i = 0; i < 4; ++i) {
                int row = wm + i * 16 + lm;
                int cc = (k2 * 4 + quad) ^ (row & 7);
                af[i] = *(const bf16x8*)&ldsA[row * 64 + cc * 8];
            }
            #pragma unroll
            for (int j = 0; j < 4; ++j) {
                int row = wn + j * 16 + lm;
                int cc = (k2 * 4 + quad) ^ (row & 7);
                bfr[j] = *(const bf16x8*)&ldsB[row * 64 + cc * 8];
            }
            #pragma unroll
            for (int i = 0; i < 4; ++i)
                #pragma unroll
                for (int j = 0; j < 4; ++j)
                    acc[i][j] = __builtin_amdgcn_mfma_f32_16x16x32_bf16(af[i], bfr[j], acc[i][j], 0, 0, 0);
        }
        __syncthreads();
    }

    // epilogue: C/D layout col = lane&15, row = quad*4 + reg
    if (mode == 0) {
        bf16_t* Ob = (bf16_t*)out;
        #pragma unroll
        for (int i = 0; i < 4; ++i) {
            #pragma unroll
            for (int j = 0; j < 4; ++j) {
                int n = n0 + wn + j * 16 + lm;
                float bv = bias[n];
                int h = n >> 7, d = n & 127;
                #pragma unroll
                for (int r = 0; r < 4; ++r) {
                    int m = m0 + wm + i * 16 + quad * 4 + r;
                    int b = m >> 11, s = m & 2047;
                    Ob[(((size_t)(b * S_NH + h)) * S_SEQ + s) * S_HD + d] =
                        (bf16_t)((acc[i][j][r] + bv) * scale);
                }
            }
        }
    } else {
        float* Of = (float*)out;
        #pragma unroll
        for (int i = 0; i < 4; ++i) {
            #pragma unroll
            for (int j = 0; j < 4; ++j) {
                int n = n0 + wn + j * 16 + lm;
                float bv = bias[n];
                #pragma unroll
                for (int r = 0; r < 4; ++r) {
                    int m = m0 + wm + i * 16 + quad * 4 + r;
                    Of[(size_t)m * S_HID + n] = acc[i][j][r] + bv;
                }
            }
        }
    }
}

// ---------------- flash attention (causal), S^T orientation ----------------
// Q,K: [bh][s][d] bf16 (Q pre-scaled by 1/sqrt(d)*log2e); Vt: [bh][d][s] bf16
// O: [b][s][h*128+d] bf16.
// Each block handles q-tiles pair and 31-pair (64 rows each) -> exactly 17
// key-tiles of work per block (triangular load balance). 512 blocks, 80KB LDS
// -> exactly 2 blocks/CU, all resident.
// Per wave: 16 q rows. Scores computed TRANSPOSED (S^T = K*Q^T): C-layout
// row = key, col = q. Softmax reductions are cross-quad (2 shuffles); P lane
// data is 4 consecutive keys -> b64 P writes / b128 P reads, conflict-free.
// PV computed as O^T = V^T * P^T (P as B-operand).
__global__ __launch_bounds__(256, 2)
void attn(const bf16_t* __restrict__ Q, const bf16_t* __restrict__ K,
          const bf16_t* __restrict__ Vt, bf16_t* __restrict__ O) {
    __shared__ __align__(16) bf16_t ldsK[128 * 128];   // 32KB
    __shared__ __align__(16) bf16_t ldsV[128 * 128];   // 32KB
    __shared__ __align__(16) bf16_t ldsP[4 * 16 * 128];// 16KB, per-wave 4KB
    const int tid = threadIdx.x, wid = tid >> 6, lane = tid & 63;
    const int lm = lane & 15, quad = lane >> 4;
    const int pair = blockIdx.x;
    const int bh = blockIdx.y;
    const int b = bh >> 4, h = bh & 15;
    bf16_t* pb = &ldsP[wid * 2048];

    for (int seg = 0; seg < 2; ++seg) {
        const int q0 = seg ? (1984 - pair * 64) : (pair * 64);
        const int qrow = q0 + wid * 16 + lm;   // this lane's q (= S^T column)

        // Q fragments (B-operand): B[k=quad*8+j][n=lm], 4 k-steps of 32 over d
        bf16x8 qf[4];
        {
            const bf16_t* qp = Q + ((size_t)bh * S_SEQ + qrow) * S_HD + quad * 8;
            #pragma unroll
            for (int ks = 0; ks < 4; ++ks) qf[ks] = *(const bf16x8*)(qp + ks * 32);
        }

        floatx4 oa[8];
        #pragma unroll
        for (int j = 0; j < 8; ++j) oa[j] = (floatx4){0.f, 0.f, 0.f, 0.f};
        float m_st = -1e30f, l_st = 0.f;

        const int nkt = (q0 + 64 + 127) >> 7;
        for (int kti = 0; kti < nkt; ++kti) {
            const int kt = kti * 128;
            // stage K-tile [128 keys x 128 d] and Vt-tile [128 d x 128 keys], swizzled
            #pragma unroll
            for (int i = 0; i < 8; ++i) {
                int slot = i * 4 + wid;             // 0..31, wave-uniform
                int row = slot * 4 + quad;          // 0..127 (1KB = 4 rows x 256B)
                int cg = lm ^ (row & 7);
                gload_lds16(K + ((size_t)bh * S_SEQ + kt + row) * S_HD + cg * 8, &ldsK[slot * 512]);
                gload_lds16(Vt + ((size_t)bh * S_HD + row) * S_SEQ + kt + cg * 8, &ldsV[slot * 512]);
            }
            __syncthreads();

            // S^T = K * Q^T : A = K-frag (rows=keys), B = Q-frag (cols=q)
            floatx4 sa[8];
            #pragma unroll
            for (int j = 0; j < 8; ++j) sa[j] = (floatx4){0.f, 0.f, 0.f, 0.f};
            #pragma unroll
            for (int ks = 0; ks < 4; ++ks) {
                #pragma unroll
                for (int j = 0; j < 8; ++j) {
                    int row = j * 16 + lm;
                    int cc = (ks * 4 + quad) ^ (row & 7);
                    bf16x8 kb = *(const bf16x8*)&ldsK[row * 128 + cc * 8];
                    sa[j] = __builtin_amdgcn_mfma_f32_16x16x32_bf16(kb, qf[ks], sa[j], 0, 0, 0);
                }
            }
            // causal mask: S^T row = key = kt + j*16 + quad*4 + r, col = qrow
            if (kti == nkt - 1) {
                #pragma unroll
                for (int j = 0; j < 8; ++j)
                    #pragma unroll
                    for (int r = 0; r < 4; ++r) {
                        int key = kt + j * 16 + quad * 4 + r;
                        if (key > qrow) sa[j][r] = -1e30f;
                    }
            }
            // online softmax over this lane's q column (cross-quad reduce)
            float mx = sa[0][0];
            #pragma unroll
            for (int j = 0; j < 8; ++j)
                #pragma unroll
                for (int r = 0; r < 4; ++r) mx = fmaxf(mx, sa[j][r]);
            mx = fmaxf(mx, __shfl_xor(mx, 16));
            mx = fmaxf(mx, __shfl_xor(mx, 32));
            float mn = fmaxf(m_st, mx);
            float al = __builtin_amdgcn_exp2f(m_st - mn);
            m_st = mn;

            float rs = 0.f;
            #pragma unroll
            for (int j = 0; j < 8; ++j) {
                bf16x4 pk;
                #pragma unroll
                for (int r = 0; r < 4; ++r) {
                    float p = __builtin_amdgcn_exp2f(sa[j][r] - mn);
                    rs += p;
                    pk[r] = (bf16_t)p;
                }
                // P[q=lm][key = j*16 + quad*4 + r], 16B-pair XOR swizzle by lm&7
                int pairidx = j * 2 + (quad >> 1);
                int chunk = ((pairidx ^ (lm & 7)) << 1) + (quad & 1);
                *(bf16x4*)&pb[lm * 128 + chunk * 4] = pk;
            }
            rs += __shfl_xor(rs, 16);
            rs += __shfl_xor(rs, 32);
            l_st = l_st * al + rs;
            #pragma unroll
            for (int j = 0; j < 8; ++j)
                #pragma unroll
                for (int r = 0; r < 4; ++r) oa[j][r] *= al;

            // O^T += V^T * P^T : A = V^T-frag (rows=d), B = P-frag (cols=q)
            #pragma unroll
            for (int ks2 = 0; ks2 < 4; ++ks2) {
                int pr = (ks2 * 4 + quad) ^ (lm & 7);
                bf16x8 pf = *(const bf16x8*)&pb[lm * 128 + pr * 8];
                #pragma unroll
                for (int jd = 0; jd < 8; ++jd) {
                    int vrow = jd * 16 + lm;
                    int vc = (ks2 * 4 + quad) ^ (vrow & 7);
                    bf16x8 vb = *(const bf16x8*)&ldsV[vrow * 128 + vc * 8];
                    oa[jd] = __builtin_amdgcn_mfma_f32_16x16x32_bf16(vb, pf, oa[jd], 0, 0, 0);
                }
            }
            __syncthreads();   // before next staging overwrites ldsK/ldsV
        }

        // epilogue: O^T C-layout: col = q = lm, row = d = jd*16 + quad*4 + r
        float inv = 1.0f / l_st;
        bf16_t* orow = O + ((size_t)b * S_SEQ + qrow) * S_HID + h * S_HD;
        #pragma unroll
        for (int jd = 0; jd < 8; ++jd) {
            bf16x4 ov;
            #pragma unroll
            for (int r = 0; r < 4; ++r) ov[r] = (bf16_t)(oa[jd][r] * inv);
            *(bf16x4*)&orow[jd * 16 + quad * 4] = ov;
        }
    }
}

extern "C" void kernel_launch(void* const* d_in, const int* in_sizes, int n_in,
                              void* d_out, int out_size, void* d_ws, size_t ws_size,
                              hipStream_t stream) {
    const float* hs = (const float*)d_in[0];
    const float* qw = (const float*)d_in[1];
    const float* kw = (const float*)d_in[2];
    const float* vw = (const float*)d_in[3];
    const float* ow = (const float*)d_in[4];
    const float* qbias = (const float*)d_in[5];
    const float* kbias = (const float*)d_in[6];
    const float* vbias = (const float*)d_in[7];
    const float* obias = (const float*)d_in[8];

    char* ws = (char*)d_ws;
    bf16_t* Xb  = (bf16_t*)(ws + 0);           // 16 MB, reused as attention output
    bf16_t* Wqb = (bf16_t*)(ws + 16777216);    // 8 MB
    bf16_t* Wkb = (bf16_t*)(ws + 25165824);
    bf16_t* Wvb = (bf16_t*)(ws + 33554432);
    bf16_t* Wob = (bf16_t*)(ws + 41943040);
    bf16_t* Qb  = (bf16_t*)(ws + 50331648);    // 16 MB each
    bf16_t* Kb  = (bf16_t*)(ws + 67108864);
    bf16_t* Vb  = (bf16_t*)(ws + 83886080);
    bf16_t* Vtb = (bf16_t*)(ws + 100663296);
    bf16_t* Ob  = Xb;                          // X dead after QKV GEMMs

    cvt_bf16<<<1024, 256, 0, stream>>>(hs, Xb, S_M * S_HID);
    cvt_bf16<<<512, 256, 0, stream>>>(qw, Wqb, S_HID * S_HID);
    cvt_bf16<<<512, 256, 0, stream>>>(kw, Wkb, S_HID * S_HID);
    cvt_bf16<<<512, 256, 0, stream>>>(vw, Wvb, S_HID * S_HID);
    cvt_bf16<<<512, 256, 0, stream>>>(ow, Wob, S_HID * S_HID);

    dim3 gg(S_HID / 128, S_M / 128);  // (16, 32)
    // fold softmax scale 1/sqrt(128) and log2(e) into Q
    const float qscale = 0.08838834764831845f * 1.4426950408889634f;
    gemm_bt<<<gg, 256, 0, stream>>>(Xb, Wqb, qbias, (void*)Qb, 0, qscale);
    gemm_bt<<<gg, 256, 0, stream>>>(Xb, Wkb, kbias, (void*)Kb, 0, 1.0f);
    gemm_bt<<<gg, 256, 0, stream>>>(Xb, Wvb, vbias, (void*)Vb, 0, 1.0f);

    transpose_v<<<dim3(2, 32, 32), 256, 0, stream>>>(Vb, Vtb);

    // triangular pairing: block (pair, bh) does q-tiles pair and 31-pair
    attn<<<dim3(16, S_BH), 256, 0, stream>>>(Qb, Kb, Vtb, Ob);

    gemm_bt<<<gg, 256, 0, stream>>>(Ob, Wob, obias, d_out, 1, 1.0f);
}

// Round 3
// 380.696 us; speedup vs baseline: 1.2245x; 1.0968x over previous
//
#include <hip/hip_runtime.h>

// Sizes are fixed by the problem.
#define S_HID 2048
#define S_SEQ 2048
#define S_B   2
#define S_NH  16
#define S_HD  128
#define S_M   (S_B * S_SEQ)   // 4096 rows
#define S_BH  (S_B * S_NH)    // 32

typedef __bf16 bf16_t;
typedef __bf16 bf16x8 __attribute__((ext_vector_type(8)));
typedef __bf16 bf16x4 __attribute__((ext_vector_type(4)));
typedef float  floatx4 __attribute__((ext_vector_type(4)));
typedef float  floatx16 __attribute__((ext_vector_type(16)));

typedef __attribute__((address_space(1))) unsigned int as1_uint;
typedef __attribute__((address_space(3))) unsigned int as3_uint;

// async global->LDS, 16B per lane; LDS dest = wave-uniform base + lane*16
__device__ __forceinline__ void gload_lds16(const void* g, void* l) {
    __builtin_amdgcn_global_load_lds((as1_uint*)g, (as3_uint*)l, 16, 0, 0);
}

// ---------------- fp32 -> bf16 convert ----------------
__global__ void cvt_bf16(const float* __restrict__ src, bf16_t* __restrict__ dst, int n) {
    int nv = n >> 2;
    int stride = gridDim.x * blockDim.x;
    for (int i = blockIdx.x * blockDim.x + threadIdx.x; i < nv; i += stride) {
        float4 v = ((const float4*)src)[i];
        bf16x4 o;
        o.x = (bf16_t)v.x; o.y = (bf16_t)v.y; o.z = (bf16_t)v.z; o.w = (bf16_t)v.w;
        ((bf16x4*)dst)[i] = o;
    }
}

// ---------------- bf16 GEMM: C = A[4096x2048] * W[2048x2048]^T + bias ----------------
// mode 0: out bf16 in [B,H,S,D] layout, value = (acc+bias)*scale   (Q/K projections)
// mode 1: out fp32 row-major [M][N], value = acc+bias              (final projection)
// mode 2: out bf16 transposed [B,H,D,S] layout (V^T)               (V projection)
__global__ __launch_bounds__(256, 2)
void gemm_bt(const bf16_t* __restrict__ A, const bf16_t* __restrict__ W,
             const float* __restrict__ bias, void* __restrict__ out,
             int mode, float scale) {
    __shared__ __align__(16) bf16_t ldsA[128 * 64];
    __shared__ __align__(16) bf16_t ldsB[128 * 64];
    const int tid = threadIdx.x;
    const int wid = tid >> 6, lane = tid & 63;
    const int m0 = blockIdx.y * 128, n0 = blockIdx.x * 128;
    const int wm = (wid & 1) * 64, wn = (wid >> 1) * 64;
    const int lm = lane & 15, quad = lane >> 4;
    const int srow = lane >> 3;   // row within 1KB slot (8 rows x 128B)
    const int scol = lane & 7;    // 16B chunk slot within row

    floatx4 acc[4][4];
    #pragma unroll
    for (int i = 0; i < 4; ++i)
        #pragma unroll
        for (int j = 0; j < 4; ++j)
            acc[i][j] = (floatx4){0.f, 0.f, 0.f, 0.f};

    for (int kt = 0; kt < S_HID; kt += 64) {
        #pragma unroll
        for (int i = 0; i < 4; ++i) {
            int slot = i * 4 + wid;             // 0..15, wave-uniform
            int row = slot * 8 + srow;          // 0..127
            int cg = scol ^ (row & 7);          // source chunk for this LDS slot pos
            gload_lds16(A + (size_t)(m0 + row) * S_HID + kt + cg * 8, &ldsA[slot * 512]);
            gload_lds16(W + (size_t)(n0 + row) * S_HID + kt + cg * 8, &ldsB[slot * 512]);
        }
        __syncthreads();
        #pragma unroll
        for (int k2 = 0; k2 < 2; ++k2) {
            bf16x8 af[4], bfr[4];
            #pragma unroll
            for (int i = 0; i < 4; ++i) {
                int row = wm + i * 16 + lm;
                int cc = (k2 * 4 + quad) ^ (row & 7);
                af[i] = *(const bf16x8*)&ldsA[row * 64 + cc * 8];
            }
            #pragma unroll
            for (int j = 0; j < 4; ++j) {
                int row = wn + j * 16 + lm;
                int cc = (k2 * 4 + quad) ^ (row & 7);
                bfr[j] = *(const bf16x8*)&ldsB[row * 64 + cc * 8];
            }
            #pragma unroll
            for (int i = 0; i < 4; ++i)
                #pragma unroll
                for (int j = 0; j < 4; ++j)
                    acc[i][j] = __builtin_amdgcn_mfma_f32_16x16x32_bf16(af[i], bfr[j], acc[i][j], 0, 0, 0);
        }
        __syncthreads();
    }

    // epilogue: C/D layout col = lane&15, row = quad*4 + reg
    if (mode == 0) {
        bf16_t* Ob = (bf16_t*)out;
        #pragma unroll
        for (int i = 0; i < 4; ++i) {
            #pragma unroll
            for (int j = 0; j < 4; ++j) {
                int n = n0 + wn + j * 16 + lm;
                float bv = bias[n];
                int h = n >> 7, d = n & 127;
                #pragma unroll
                for (int r = 0; r < 4; ++r) {
                    int m = m0 + wm + i * 16 + quad * 4 + r;
                    int b = m >> 11, s = m & 2047;
                    Ob[(((size_t)(b * S_NH + h)) * S_SEQ + s) * S_HD + d] =
                        (bf16_t)((acc[i][j][r] + bv) * scale);
                }
            }
        }
    } else if (mode == 1) {
        float* Of = (float*)out;
        #pragma unroll
        for (int i = 0; i < 4; ++i) {
            #pragma unroll
            for (int j = 0; j < 4; ++j) {
                int n = n0 + wn + j * 16 + lm;
                float bv = bias[n];
                #pragma unroll
                for (int r = 0; r < 4; ++r) {
                    int m = m0 + wm + i * 16 + quad * 4 + r;
                    Of[(size_t)m * S_HID + n] = acc[i][j][r] + bv;
                }
            }
        }
    } else {
        // V^T: out[((b*16+h)*128 + d) * 2048 + s], 4 consecutive s per store
        bf16_t* Vt = (bf16_t*)out;
        #pragma unroll
        for (int i = 0; i < 4; ++i) {
            #pragma unroll
            for (int j = 0; j < 4; ++j) {
                int n = n0 + wn + j * 16 + lm;
                float bv = bias[n];
                int h = n >> 7, d = n & 127;
                int m = m0 + wm + i * 16 + quad * 4;
                int b = m >> 11, s = m & 2047;
                bf16x4 ov;
                #pragma unroll
                for (int r = 0; r < 4; ++r) ov[r] = (bf16_t)(acc[i][j][r] + bv);
                *(bf16x4*)&Vt[(((size_t)(b * S_NH + h)) * S_HD + d) * S_SEQ + s] = ov;
            }
        }
    }
}

// Build PV B-fragment (16 keys) from packed P values via cross-half exchange.
// lo = local keys {base+0..3 (+4h)}, hi = local keys {base+8..11 (+4h)}.
__device__ __forceinline__ bf16x8 make_pfrag(bf16x4 lo, bf16x4 hi, int h) {
    int2 li = __builtin_bit_cast(int2, lo);
    int2 hh = __builtin_bit_cast(int2, hi);
    int2 xl, xh;
    xl.x = __shfl_xor(li.x, 32); xl.y = __shfl_xor(li.y, 32);
    xh.x = __shfl_xor(hh.x, 32); xh.y = __shfl_xor(hh.y, 32);
    int2 flo, fhi;
    flo.x = h ? xh.x : li.x;  flo.y = h ? xh.y : li.y;
    fhi.x = h ? hh.x : xl.x;  fhi.y = h ? hh.y : xl.y;
    bf16x4 a = __builtin_bit_cast(bf16x4, flo);
    bf16x4 b = __builtin_bit_cast(bf16x4, fhi);
    return __builtin_shufflevector(a, b, 0, 1, 2, 3, 4, 5, 6, 7);
}

// ---------------- flash attention (causal), S^T orientation, 32x32 MFMA ----------------
// Q,K: [bh][s][d] bf16 (Q pre-scaled by 1/sqrt(d)*log2e); Vt: [bh][d][s] bf16
// O: [b][s][h*128+d] bf16.
// Grid 256 blocks: bh = bx&31 (same-bh blocks share XCD), pair = bx>>5.
// Block = 4 waves x 32 q = 128-q tile; processes q-tile pair and 15-pair
// (17 key-tiles total, perfectly balanced). K/V double-buffered (128KB LDS,
// 1 block/CU); prefetch of tile n+1 issued right AFTER the barrier so the
// vmcnt(0) drain before the next barrier lands after a full compute window.
__global__ __launch_bounds__(256, 1)
void attn(const bf16_t* __restrict__ Q, const bf16_t* __restrict__ K,
          const bf16_t* __restrict__ Vt, bf16_t* __restrict__ O) {
    __shared__ __align__(16) bf16_t ldsK[2][128 * 128];   // 2 x 32KB
    __shared__ __align__(16) bf16_t ldsV[2][128 * 128];   // 2 x 32KB
    const int tid = threadIdx.x, wid = tid >> 6, lane = tid & 63;
    const int lm = lane & 15, quad = lane >> 4;      // staging roles
    const int c31 = lane & 31, h = lane >> 5, r7 = lane & 7;  // compute roles
    const int bx = blockIdx.x;
    const int bh = bx & 31, pair = bx >> 5;
    const int b = bh >> 4, hd = bh & 15;

    const bf16_t* Kbase = K + (size_t)bh * S_SEQ * S_HD;
    const bf16_t* Vbase = Vt + (size_t)bh * S_HD * S_SEQ;

    int pp = 0;
    #pragma unroll
    for (int seg = 0; seg < 2; ++seg) {
        const int q0 = seg ? (1920 - pair * 128) : (pair * 128);
        const int qcol = q0 + wid * 32 + c31;      // this lane's q (= S^T column)
        const int nkt = (q0 >> 7) + 1;

        // Q fragments (B-operand): B[k = ks*16 + h*8 + j][n = c31]
        bf16x8 qf[8];
        {
            const bf16_t* qp = Q + ((size_t)bh * S_SEQ + qcol) * S_HD + h * 8;
            #pragma unroll
            for (int ks = 0; ks < 8; ++ks) qf[ks] = *(const bf16x8*)(qp + ks * 16);
        }

        floatx16 oa[4];
        #pragma unroll
        for (int jd = 0; jd < 4; ++jd)
            #pragma unroll
            for (int e = 0; e < 16; ++e) oa[jd][e] = 0.f;
        float m_st = -1e30f, l_st = 0.f;

        // stage tile 0 into buf pp (safe: no wave reads buf pp at this point)
        {
            #pragma unroll
            for (int i = 0; i < 8; ++i) {
                int slot = i * 4 + wid;
                int row = slot * 4 + quad;
                int cg = lm ^ (row & 7);
                gload_lds16(Kbase + (size_t)row * S_HD + cg * 8, &ldsK[pp][slot * 512]);
                gload_lds16(Vbase + (size_t)row * S_SEQ + cg * 8, &ldsV[pp][slot * 512]);
            }
        }

        for (int kti = 0; kti < nkt; ++kti) {
            const int kt = kti * 128;
            __syncthreads();   // drains staging of tile kti (and everything older)

            if (kti + 1 < nkt) {   // prefetch tile kti+1 into the other buffer
                const int ktn = kt + 128;
                #pragma unroll
                for (int i = 0; i < 8; ++i) {
                    int slot = i * 4 + wid;
                    int row = slot * 4 + quad;
                    int cg = lm ^ (row & 7);
                    gload_lds16(Kbase + (size_t)(ktn + row) * S_HD + cg * 8, &ldsK[pp ^ 1][slot * 512]);
                    gload_lds16(Vbase + (size_t)row * S_SEQ + ktn + cg * 8, &ldsV[pp ^ 1][slot * 512]);
                }
            }

            // S^T = K * Q^T : A = K-frag (rows=keys), B = Q-frag (cols=q)
            floatx16 sa[4];
            #pragma unroll
            for (int jr = 0; jr < 4; ++jr)
                #pragma unroll
                for (int e = 0; e < 16; ++e) sa[jr][e] = 0.f;
            #pragma unroll
            for (int ks = 0; ks < 8; ++ks) {
                #pragma unroll
                for (int jr = 0; jr < 4; ++jr) {
                    int row = jr * 32 + c31;
                    bf16x8 kf = *(const bf16x8*)&ldsK[pp][row * 128 + (((ks * 2 + h) ^ r7)) * 8];
                    sa[jr] = __builtin_amdgcn_mfma_f32_32x32x16_bf16(kf, qf[ks], sa[jr], 0, 0, 0);
                }
            }

            // causal mask on the diagonal tile: key = kt + jr*32 + (r&3)+8*(r>>2)+4h
            if (kti == nkt - 1) {
                #pragma unroll
                for (int jr = 0; jr < 4; ++jr)
                    #pragma unroll
                    for (int rr = 0; rr < 16; ++rr) {
                        int key = kt + jr * 32 + (rr & 3) + 8 * (rr >> 2) + 4 * h;
                        if (key > qcol) sa[jr][rr] = -1e30f;
                    }
            }

            // online softmax over this lane's q column (one cross-half shuffle)
            float mx = -1e30f;
            #pragma unroll
            for (int jr = 0; jr < 4; ++jr)
                #pragma unroll
                for (int rr = 0; rr < 16; ++rr) mx = fmaxf(mx, sa[jr][rr]);
            mx = fmaxf(mx, __shfl_xor(mx, 32));
            float mn = fmaxf(m_st, mx);
            float al = __builtin_amdgcn_exp2f(m_st - mn);
            m_st = mn;

            float rs = 0.f;
            bf16x8 pf[8];
            #pragma unroll
            for (int jr = 0; jr < 4; ++jr) {
                bf16x4 pk[4];
                #pragma unroll
                for (int g = 0; g < 4; ++g)
                    #pragma unroll
                    for (int e = 0; e < 4; ++e) {
                        float p = __builtin_amdgcn_exp2f(sa[jr][g * 4 + e] - mn);
                        rs += p;
                        pk[g][e] = (bf16_t)p;
                    }
                pf[jr * 2]     = make_pfrag(pk[0], pk[1], h);
                pf[jr * 2 + 1] = make_pfrag(pk[2], pk[3], h);
            }
            rs += __shfl_xor(rs, 32);
            l_st = l_st * al + rs;
            #pragma unroll
            for (int jd = 0; jd < 4; ++jd)
                #pragma unroll
                for (int e = 0; e < 16; ++e) oa[jd][e] *= al;

            // O^T += V^T * P^T : A = V^T-frag (rows=d), B = P-frag (cols=q)
            #pragma unroll
            for (int kb = 0; kb < 8; ++kb) {
                #pragma unroll
                for (int jd = 0; jd < 4; ++jd) {
                    int row = jd * 32 + c31;
                    bf16x8 vf = *(const bf16x8*)&ldsV[pp][row * 128 + (((kb * 2 + h) ^ r7)) * 8];
                    oa[jd] = __builtin_amdgcn_mfma_f32_32x32x16_bf16(vf, pf[kb], oa[jd], 0, 0, 0);
                }
            }
            pp ^= 1;
        }

        // epilogue: O^T C-layout: col q = c31(+base), row d = jd*32 + (r&3)+8*(r>>2)+4h
        float inv = 1.0f / l_st;
        bf16_t* op = O + ((size_t)b * S_SEQ + qcol) * S_HID + hd * S_HD;
        #pragma unroll
        for (int jd = 0; jd < 4; ++jd)
            #pragma unroll
            for (int g = 0; g < 4; ++g) {
                bf16x4 ov;
                #pragma unroll
                for (int e = 0; e < 4; ++e) ov[e] = (bf16_t)(oa[jd][g * 4 + e] * inv);
                *(bf16x4*)&op[jd * 32 + g * 8 + 4 * h] = ov;
            }
    }
}

extern "C" void kernel_launch(void* const* d_in, const int* in_sizes, int n_in,
                              void* d_out, int out_size, void* d_ws, size_t ws_size,
                              hipStream_t stream) {
    const float* hs = (const float*)d_in[0];
    const float* qw = (const float*)d_in[1];
    const float* kw = (const float*)d_in[2];
    const float* vw = (const float*)d_in[3];
    const float* ow = (const float*)d_in[4];
    const float* qbias = (const float*)d_in[5];
    const float* kbias = (const float*)d_in[6];
    const float* vbias = (const float*)d_in[7];
    const float* obias = (const float*)d_in[8];

    char* ws = (char*)d_ws;
    bf16_t* Xb  = (bf16_t*)(ws + 0);           // 16 MB, reused as attention output
    bf16_t* Wqb = (bf16_t*)(ws + 16777216);    // 8 MB
    bf16_t* Wkb = (bf16_t*)(ws + 25165824);
    bf16_t* Wvb = (bf16_t*)(ws + 33554432);
    bf16_t* Wob = (bf16_t*)(ws + 41943040);
    bf16_t* Qb  = (bf16_t*)(ws + 50331648);    // 16 MB each
    bf16_t* Kb  = (bf16_t*)(ws + 67108864);
    bf16_t* Vtb = (bf16_t*)(ws + 83886080);
    bf16_t* Ob  = Xb;                          // X dead after QKV GEMMs

    cvt_bf16<<<1024, 256, 0, stream>>>(hs, Xb, S_M * S_HID);
    cvt_bf16<<<512, 256, 0, stream>>>(qw, Wqb, S_HID * S_HID);
    cvt_bf16<<<512, 256, 0, stream>>>(kw, Wkb, S_HID * S_HID);
    cvt_bf16<<<512, 256, 0, stream>>>(vw, Wvb, S_HID * S_HID);
    cvt_bf16<<<512, 256, 0, stream>>>(ow, Wob, S_HID * S_HID);

    dim3 gg(S_HID / 128, S_M / 128);  // (16, 32)
    // fold softmax scale 1/sqrt(128) and log2(e) into Q
    const float qscale = 0.08838834764831845f * 1.4426950408889634f;
    gemm_bt<<<gg, 256, 0, stream>>>(Xb, Wqb, qbias, (void*)Qb, 0, qscale);
    gemm_bt<<<gg, 256, 0, stream>>>(Xb, Wkb, kbias, (void*)Kb, 0, 1.0f);
    gemm_bt<<<gg, 256, 0, stream>>>(Xb, Wvb, vbias, (void*)Vtb, 2, 1.0f);

    // 256 blocks: bh = bx&31 (same-bh blocks land on same XCD), pair = bx>>5
    attn<<<256, 256, 0, stream>>>(Qb, Kb, Vtb, Ob);

    gemm_bt<<<gg, 256, 0, stream>>>(Ob, Wob, obias, d_out, 1, 1.0f);
}

// Round 4
// 364.439 us; speedup vs baseline: 1.2791x; 1.0446x over previous
//
#include <hip/hip_runtime.h>

// Sizes are fixed by the problem.
#define S_HID 2048
#define S_SEQ 2048
#define S_B   2
#define S_NH  16
#define S_HD  128
#define S_M   (S_B * S_SEQ)   // 4096 rows
#define S_BH  (S_B * S_NH)    // 32

typedef __bf16 bf16_t;
typedef __bf16 bf16x8 __attribute__((ext_vector_type(8)));
typedef __bf16 bf16x4 __attribute__((ext_vector_type(4)));
typedef float  floatx4 __attribute__((ext_vector_type(4)));
typedef float  floatx16 __attribute__((ext_vector_type(16)));

typedef __attribute__((address_space(1))) unsigned int as1_uint;
typedef __attribute__((address_space(3))) unsigned int as3_uint;

// async global->LDS, 16B per lane; LDS dest = wave-uniform base + lane*16
__device__ __forceinline__ void gload_lds16(const void* g, void* l) {
    __builtin_amdgcn_global_load_lds((as1_uint*)g, (as3_uint*)l, 16, 0, 0);
}

// ---------------- fp32 -> bf16 convert (X) ----------------
__global__ void cvt_bf16(const float* __restrict__ src, bf16_t* __restrict__ dst, int n) {
    int nv = n >> 2;
    int stride = gridDim.x * blockDim.x;
    for (int i = blockIdx.x * blockDim.x + threadIdx.x; i < nv; i += stride) {
        float4 v = ((const float4*)src)[i];
        bf16x4 o;
        o.x = (bf16_t)v.x; o.y = (bf16_t)v.y; o.z = (bf16_t)v.z; o.w = (bf16_t)v.w;
        ((bf16x4*)dst)[i] = o;
    }
}

// ---------------- fp32 -> bf16 convert, 4 weights -> contiguous [q|k|v|o] ----------------
__global__ void cvt_w4(const float* __restrict__ q, const float* __restrict__ k,
                       const float* __restrict__ v, const float* __restrict__ o,
                       bf16_t* __restrict__ dst) {
    const int per = (S_HID * S_HID) >> 2;    // vec4 elements per matrix (2^20)
    const int total = per * 4;
    int stride = gridDim.x * blockDim.x;
    for (int i = blockIdx.x * blockDim.x + threadIdx.x; i < total; i += stride) {
        int region = i >> 20;
        int local = i & (per - 1);
        const float* src = region == 0 ? q : region == 1 ? k : region == 2 ? v : o;
        float4 x = ((const float4*)src)[local];
        bf16x4 y;
        y.x = (bf16_t)x.x; y.y = (bf16_t)x.y; y.z = (bf16_t)x.z; y.w = (bf16_t)x.w;
        ((bf16x4*)dst)[i] = y;
    }
}

// ---------------- fused QKV GEMM ----------------
// A[4096x2048] bf16, Wqkv stacked [6144x2048] bf16 (rows 0-2047 Q, 2048-4095 K,
// 4096-6143 V). Grid (48, 32). Epilogue per region:
//   Q: bf16 [B,H,S,D], value=(acc+bias)*qscale  (softmax scale + log2e folded)
//   K: bf16 [B,H,S,D], value=acc+bias
//   V: bf16 [B,H,D,S] transposed, value=acc+bias
__global__ __launch_bounds__(256, 3)
void gemm_qkv(const bf16_t* __restrict__ A, const bf16_t* __restrict__ W,
              const float* __restrict__ qbias, const float* __restrict__ kbias,
              const float* __restrict__ vbias,
              bf16_t* __restrict__ Qo, bf16_t* __restrict__ Ko, bf16_t* __restrict__ Vto,
              float qscale) {
    __shared__ __align__(16) bf16_t ldsA[128 * 64];
    __shared__ __align__(16) bf16_t ldsB[128 * 64];
    const int tid = threadIdx.x;
    const int wid = tid >> 6, lane = tid & 63;
    const int m0 = blockIdx.y * 128, n0 = blockIdx.x * 128;
    const int wm = (wid & 1) * 64, wn = (wid >> 1) * 64;
    const int lm = lane & 15, quad = lane >> 4;
    const int srow = lane >> 3;
    const int scol = lane & 7;

    floatx4 acc[4][4];
    #pragma unroll
    for (int i = 0; i < 4; ++i)
        #pragma unroll
        for (int j = 0; j < 4; ++j)
            acc[i][j] = (floatx4){0.f, 0.f, 0.f, 0.f};

    for (int kt = 0; kt < S_HID; kt += 64) {
        #pragma unroll
        for (int i = 0; i < 4; ++i) {
            int slot = i * 4 + wid;
            int row = slot * 8 + srow;
            int cg = scol ^ (row & 7);
            gload_lds16(A + (size_t)(m0 + row) * S_HID + kt + cg * 8, &ldsA[slot * 512]);
            gload_lds16(W + (size_t)(n0 + row) * S_HID + kt + cg * 8, &ldsB[slot * 512]);
        }
        __syncthreads();
        #pragma unroll
        for (int k2 = 0; k2 < 2; ++k2) {
            bf16x8 af[4], bfr[4];
            #pragma unroll
            for (int i = 0; i < 4; ++i) {
                int row = wm + i * 16 + lm;
                int cc = (k2 * 4 + quad) ^ (row & 7);
                af[i] = *(const bf16x8*)&ldsA[row * 64 + cc * 8];
            }
            #pragma unroll
            for (int j = 0; j < 4; ++j) {
                int row = wn + j * 16 + lm;
                int cc = (k2 * 4 + quad) ^ (row & 7);
                bfr[j] = *(const bf16x8*)&ldsB[row * 64 + cc * 8];
            }
            #pragma unroll
            for (int i = 0; i < 4; ++i)
                #pragma unroll
                for (int j = 0; j < 4; ++j)
                    acc[i][j] = __builtin_amdgcn_mfma_f32_16x16x32_bf16(af[i], bfr[j], acc[i][j], 0, 0, 0);
        }
        __syncthreads();
    }

    const int region = n0 >> 11;   // 0=Q, 1=K, 2=V (wave-uniform)
    if (region < 2) {
        bf16_t* Ob = region ? Ko : Qo;
        const float* bias = region ? kbias : qbias;
        float scale = region ? 1.0f : qscale;
        #pragma unroll
        for (int i = 0; i < 4; ++i) {
            #pragma unroll
            for (int j = 0; j < 4; ++j) {
                int n = n0 + wn + j * 16 + lm;
                float bv = bias[n & 2047];
                int nl = n & 2047;
                int h = nl >> 7, d = nl & 127;
                #pragma unroll
                for (int r = 0; r < 4; ++r) {
                    int m = m0 + wm + i * 16 + quad * 4 + r;
                    int b = m >> 11, s = m & 2047;
                    Ob[(((size_t)(b * S_NH + h)) * S_SEQ + s) * S_HD + d] =
                        (bf16_t)((acc[i][j][r] + bv) * scale);
                }
            }
        }
    } else {
        // V^T: out[((b*16+h)*128 + d) * 2048 + s], 4 consecutive s per store
        #pragma unroll
        for (int i = 0; i < 4; ++i) {
            #pragma unroll
            for (int j = 0; j < 4; ++j) {
                int n = n0 + wn + j * 16 + lm;
                int nl = n & 2047;
                float bv = vbias[nl];
                int h = nl >> 7, d = nl & 127;
                int m = m0 + wm + i * 16 + quad * 4;
                int b = m >> 11, s = m & 2047;
                bf16x4 ov;
                #pragma unroll
                for (int r = 0; r < 4; ++r) ov[r] = (bf16_t)(acc[i][j][r] + bv);
                *(bf16x4*)&Vto[(((size_t)(b * S_NH + h)) * S_HD + d) * S_SEQ + s] = ov;
            }
        }
    }
}

// ---------------- output GEMM: out = A[4096x2048] * W[2048x2048]^T + bias (fp32) ----------------
__global__ __launch_bounds__(256, 3)
void gemm_out(const bf16_t* __restrict__ A, const bf16_t* __restrict__ W,
              const float* __restrict__ bias, float* __restrict__ out) {
    __shared__ __align__(16) bf16_t ldsA[128 * 64];
    __shared__ __align__(16) bf16_t ldsB[128 * 64];
    const int tid = threadIdx.x;
    const int wid = tid >> 6, lane = tid & 63;
    const int m0 = blockIdx.y * 128, n0 = blockIdx.x * 128;
    const int wm = (wid & 1) * 64, wn = (wid >> 1) * 64;
    const int lm = lane & 15, quad = lane >> 4;
    const int srow = lane >> 3;
    const int scol = lane & 7;

    floatx4 acc[4][4];
    #pragma unroll
    for (int i = 0; i < 4; ++i)
        #pragma unroll
        for (int j = 0; j < 4; ++j)
            acc[i][j] = (floatx4){0.f, 0.f, 0.f, 0.f};

    for (int kt = 0; kt < S_HID; kt += 64) {
        #pragma unroll
        for (int i = 0; i < 4; ++i) {
            int slot = i * 4 + wid;
            int row = slot * 8 + srow;
            int cg = scol ^ (row & 7);
            gload_lds16(A + (size_t)(m0 + row) * S_HID + kt + cg * 8, &ldsA[slot * 512]);
            gload_lds16(W + (size_t)(n0 + row) * S_HID + kt + cg * 8, &ldsB[slot * 512]);
        }
        __syncthreads();
        #pragma unroll
        for (int k2 = 0; k2 < 2; ++k2) {
            bf16x8 af[4], bfr[4];
            #pragma unroll
            for (int i = 0; i < 4; ++i) {
                int row = wm + i * 16 + lm;
                int cc = (k2 * 4 + quad) ^ (row & 7);
                af[i] = *(const bf16x8*)&ldsA[row * 64 + cc * 8];
            }
            #pragma unroll
            for (int j = 0; j < 4; ++j) {
                int row = wn + j * 16 + lm;
                int cc = (k2 * 4 + quad) ^ (row & 7);
                bfr[j] = *(const bf16x8*)&ldsB[row * 64 + cc * 8];
            }
            #pragma unroll
            for (int i = 0; i < 4; ++i)
                #pragma unroll
                for (int j = 0; j < 4; ++j)
                    acc[i][j] = __builtin_amdgcn_mfma_f32_16x16x32_bf16(af[i], bfr[j], acc[i][j], 0, 0, 0);
        }
        __syncthreads();
    }

    #pragma unroll
    for (int i = 0; i < 4; ++i) {
        #pragma unroll
        for (int j = 0; j < 4; ++j) {
            int n = n0 + wn + j * 16 + lm;
            float bv = bias[n];
            #pragma unroll
            for (int r = 0; r < 4; ++r) {
                int m = m0 + wm + i * 16 + quad * 4 + r;
                out[(size_t)m * S_HID + n] = acc[i][j][r] + bv;
            }
        }
    }
}

// Build PV B-fragment (16 keys) from packed P values via cross-half exchange.
__device__ __forceinline__ bf16x8 make_pfrag(bf16x4 lo, bf16x4 hi, int h) {
    int2 li = __builtin_bit_cast(int2, lo);
    int2 hh = __builtin_bit_cast(int2, hi);
    int2 xl, xh;
    xl.x = __shfl_xor(li.x, 32); xl.y = __shfl_xor(li.y, 32);
    xh.x = __shfl_xor(hh.x, 32); xh.y = __shfl_xor(hh.y, 32);
    int2 flo, fhi;
    flo.x = h ? xh.x : li.x;  flo.y = h ? xh.y : li.y;
    fhi.x = h ? hh.x : xl.x;  fhi.y = h ? hh.y : xl.y;
    bf16x4 a = __builtin_bit_cast(bf16x4, flo);
    bf16x4 b = __builtin_bit_cast(bf16x4, fhi);
    return __builtin_shufflevector(a, b, 0, 1, 2, 3, 4, 5, 6, 7);
}

// ---------------- flash attention (causal), S^T orientation, 32x32 MFMA ----------------
__global__ __launch_bounds__(256, 1)
void attn(const bf16_t* __restrict__ Q, const bf16_t* __restrict__ K,
          const bf16_t* __restrict__ Vt, bf16_t* __restrict__ O) {
    __shared__ __align__(16) bf16_t ldsK[2][128 * 128];   // 2 x 32KB
    __shared__ __align__(16) bf16_t ldsV[2][128 * 128];   // 2 x 32KB
    const int tid = threadIdx.x, wid = tid >> 6, lane = tid & 63;
    const int lm = lane & 15, quad = lane >> 4;      // staging roles
    const int c31 = lane & 31, h = lane >> 5, r7 = lane & 7;  // compute roles
    const int bx = blockIdx.x;
    const int bh = bx & 31, pair = bx >> 5;
    const int b = bh >> 4, hd = bh & 15;

    const bf16_t* Kbase = K + (size_t)bh * S_SEQ * S_HD;
    const bf16_t* Vbase = Vt + (size_t)bh * S_HD * S_SEQ;

    int pp = 0;
    #pragma unroll
    for (int seg = 0; seg < 2; ++seg) {
        const int q0 = seg ? (1920 - pair * 128) : (pair * 128);
        const int qcol = q0 + wid * 32 + c31;      // this lane's q (= S^T column)
        const int nkt = (q0 >> 7) + 1;

        // Q fragments (B-operand): B[k = ks*16 + h*8 + j][n = c31]
        bf16x8 qf[8];
        {
            const bf16_t* qp = Q + ((size_t)bh * S_SEQ + qcol) * S_HD + h * 8;
            #pragma unroll
            for (int ks = 0; ks < 8; ++ks) qf[ks] = *(const bf16x8*)(qp + ks * 16);
        }

        floatx16 oa[4];
        #pragma unroll
        for (int jd = 0; jd < 4; ++jd)
            #pragma unroll
            for (int e = 0; e < 16; ++e) oa[jd][e] = 0.f;
        float m_st = -1e30f, l_st = 0.f;

        // stage tile 0 into buf pp
        {
            #pragma unroll
            for (int i = 0; i < 8; ++i) {
                int slot = i * 4 + wid;
                int row = slot * 4 + quad;
                int cg = lm ^ (row & 7);
                gload_lds16(Kbase + (size_t)row * S_HD + cg * 8, &ldsK[pp][slot * 512]);
                gload_lds16(Vbase + (size_t)row * S_SEQ + cg * 8, &ldsV[pp][slot * 512]);
            }
        }

        for (int kti = 0; kti < nkt; ++kti) {
            const int kt = kti * 128;
            __syncthreads();   // drains staging of tile kti

            if (kti + 1 < nkt) {   // prefetch tile kti+1 into the other buffer
                const int ktn = kt + 128;
                #pragma unroll
                for (int i = 0; i < 8; ++i) {
                    int slot = i * 4 + wid;
                    int row = slot * 4 + quad;
                    int cg = lm ^ (row & 7);
                    gload_lds16(Kbase + (size_t)(ktn + row) * S_HD + cg * 8, &ldsK[pp ^ 1][slot * 512]);
                    gload_lds16(Vbase + (size_t)row * S_SEQ + ktn + cg * 8, &ldsV[pp ^ 1][slot * 512]);
                }
            }

            // S^T = K * Q^T
            floatx16 sa[4];
            #pragma unroll
            for (int jr = 0; jr < 4; ++jr)
                #pragma unroll
                for (int e = 0; e < 16; ++e) sa[jr][e] = 0.f;
            #pragma unroll
            for (int ks = 0; ks < 8; ++ks) {
                #pragma unroll
                for (int jr = 0; jr < 4; ++jr) {
                    int row = jr * 32 + c31;
                    bf16x8 kf = *(const bf16x8*)&ldsK[pp][row * 128 + (((ks * 2 + h) ^ r7)) * 8];
                    sa[jr] = __builtin_amdgcn_mfma_f32_32x32x16_bf16(kf, qf[ks], sa[jr], 0, 0, 0);
                }
            }

            // causal mask on the diagonal tile
            if (kti == nkt - 1) {
                #pragma unroll
                for (int jr = 0; jr < 4; ++jr)
                    #pragma unroll
                    for (int rr = 0; rr < 16; ++rr) {
                        int key = kt + jr * 32 + (rr & 3) + 8 * (rr >> 2) + 4 * h;
                        if (key > qcol) sa[jr][rr] = -1e30f;
                    }
            }

            // online softmax over this lane's q column
            float mx = -1e30f;
            #pragma unroll
            for (int jr = 0; jr < 4; ++jr)
                #pragma unroll
                for (int rr = 0; rr < 16; ++rr) mx = fmaxf(mx, sa[jr][rr]);
            mx = fmaxf(mx, __shfl_xor(mx, 32));
            float mn = fmaxf(m_st, mx);
            float al = __builtin_amdgcn_exp2f(m_st - mn);
            m_st = mn;

            float rs = 0.f;
            bf16x8 pf[8];
            #pragma unroll
            for (int jr = 0; jr < 4; ++jr) {
                bf16x4 pk[4];
                #pragma unroll
                for (int g = 0; g < 4; ++g)
                    #pragma unroll
                    for (int e = 0; e < 4; ++e) {
                        float p = __builtin_amdgcn_exp2f(sa[jr][g * 4 + e] - mn);
                        rs += p;
                        pk[g][e] = (bf16_t)p;
                    }
                pf[jr * 2]     = make_pfrag(pk[0], pk[1], h);
                pf[jr * 2 + 1] = make_pfrag(pk[2], pk[3], h);
            }
            rs += __shfl_xor(rs, 32);
            l_st = l_st * al + rs;
            #pragma unroll
            for (int jd = 0; jd < 4; ++jd)
                #pragma unroll
                for (int e = 0; e < 16; ++e) oa[jd][e] *= al;

            // O^T += V^T * P^T
            #pragma unroll
            for (int kb = 0; kb < 8; ++kb) {
                #pragma unroll
                for (int jd = 0; jd < 4; ++jd) {
                    int row = jd * 32 + c31;
                    bf16x8 vf = *(const bf16x8*)&ldsV[pp][row * 128 + (((kb * 2 + h) ^ r7)) * 8];
                    oa[jd] = __builtin_amdgcn_mfma_f32_32x32x16_bf16(vf, pf[kb], oa[jd], 0, 0, 0);
                }
            }
            pp ^= 1;
        }

        // epilogue: O^T C-layout: col q = qcol, row d = jd*32 + (r&3)+8*(r>>2)+4h
        float inv = 1.0f / l_st;
        bf16_t* op = O + ((size_t)b * S_SEQ + qcol) * S_HID + hd * S_HD;
        #pragma unroll
        for (int jd = 0; jd < 4; ++jd)
            #pragma unroll
            for (int g = 0; g < 4; ++g) {
                bf16x4 ov;
                #pragma unroll
                for (int e = 0; e < 4; ++e) ov[e] = (bf16_t)(oa[jd][g * 4 + e] * inv);
                *(bf16x4*)&op[jd * 32 + g * 8 + 4 * h] = ov;
            }
    }
}

extern "C" void kernel_launch(void* const* d_in, const int* in_sizes, int n_in,
                              void* d_out, int out_size, void* d_ws, size_t ws_size,
                              hipStream_t stream) {
    const float* hs = (const float*)d_in[0];
    const float* qw = (const float*)d_in[1];
    const float* kw = (const float*)d_in[2];
    const float* vw = (const float*)d_in[3];
    const float* ow = (const float*)d_in[4];
    const float* qbias = (const float*)d_in[5];
    const float* kbias = (const float*)d_in[6];
    const float* vbias = (const float*)d_in[7];
    const float* obias = (const float*)d_in[8];

    char* ws = (char*)d_ws;
    bf16_t* Xb   = (bf16_t*)(ws + 0);           // 16 MB, reused as attention output
    bf16_t* Wqkv = (bf16_t*)(ws + 16777216);    // 24 MB stacked [q|k|v]
    bf16_t* Wob  = (bf16_t*)(ws + 41943040);    // 8 MB (contiguous after Wqkv)
    bf16_t* Qb   = (bf16_t*)(ws + 50331648);    // 16 MB each
    bf16_t* Kb   = (bf16_t*)(ws + 67108864);
    bf16_t* Vtb  = (bf16_t*)(ws + 83886080);
    bf16_t* Ob   = Xb;                          // X dead after QKV GEMM

    cvt_bf16<<<1024, 256, 0, stream>>>(hs, Xb, S_M * S_HID);
    cvt_w4<<<1024, 256, 0, stream>>>(qw, kw, vw, ow, Wqkv);  // writes Wqkv + Wob

    // fold softmax scale 1/sqrt(128) and log2(e) into Q
    const float qscale = 0.08838834764831845f * 1.4426950408889634f;
    gemm_qkv<<<dim3(48, 32), 256, 0, stream>>>(Xb, Wqkv, qbias, kbias, vbias,
                                               Qb, Kb, Vtb, qscale);

    // 256 blocks: bh = bx&31 (same-bh blocks land on same XCD), pair = bx>>5
    attn<<<256, 256, 0, stream>>>(Qb, Kb, Vtb, Ob);

    gemm_out<<<dim3(16, 32), 256, 0, stream>>>(Ob, Wob, obias, (float*)d_out);
}

// Round 6
// 357.027 us; speedup vs baseline: 1.3057x; 1.0208x over previous
//
#include <hip/hip_runtime.h>

// Sizes are fixed by the problem.
#define S_HID 2048
#define S_SEQ 2048
#define S_B   2
#define S_NH  16
#define S_HD  128
#define S_M   (S_B * S_SEQ)   // 4096 rows
#define S_BH  (S_B * S_NH)    // 32

typedef __bf16 bf16_t;
typedef __bf16 bf16x8 __attribute__((ext_vector_type(8)));
typedef __bf16 bf16x4 __attribute__((ext_vector_type(4)));
typedef float  floatx4 __attribute__((ext_vector_type(4)));
typedef float  floatx16 __attribute__((ext_vector_type(16)));

typedef __attribute__((address_space(1))) unsigned int as1_uint;
typedef __attribute__((address_space(3))) unsigned int as3_uint;

// async global->LDS, 16B per lane; LDS dest = wave-uniform base + lane*16
__device__ __forceinline__ void gload_lds16(const void* g, void* l) {
    __builtin_amdgcn_global_load_lds((as1_uint*)g, (as3_uint*)l, 16, 0, 0);
}

// ---------------- fp32 -> bf16 convert: X + all 4 weights in one launch ----------------
__global__ void cvt_all(const float* __restrict__ x,
                        const float* __restrict__ qw, const float* __restrict__ kw,
                        const float* __restrict__ vw, const float* __restrict__ ow,
                        bf16_t* __restrict__ Xb, bf16_t* __restrict__ Wqkv) {
    const int XV = (S_M * S_HID) >> 2;      // 2^21 vec4
    const int WV = (S_HID * S_HID) >> 2;    // 2^20 vec4 per weight
    const int total = XV + 4 * WV;
    int stride = gridDim.x * blockDim.x;
    for (int i = blockIdx.x * blockDim.x + threadIdx.x; i < total; i += stride) {
        const float* src;
        bf16x4* dst;
        int local;
        if (i < XV) {
            src = x; local = i; dst = (bf16x4*)Xb;
        } else {
            int j = i - XV;
            int r = j >> 20;
            local = j & (WV - 1);
            src = r == 0 ? qw : r == 1 ? kw : r == 2 ? vw : ow;
            dst = (bf16x4*)Wqkv + (size_t)r * WV;
        }
        float4 v = ((const float4*)src)[local];
        bf16x4 o;
        o.x = (bf16_t)v.x; o.y = (bf16_t)v.y; o.z = (bf16_t)v.z; o.w = (bf16_t)v.w;
        dst[local] = o;
    }
}

// ---------------- fused QKV GEMM ----------------
// A[4096x2048] bf16, Wqkv stacked [6144x2048] bf16. Grid (48, 32).
__global__ __launch_bounds__(256, 3)
void gemm_qkv(const bf16_t* __restrict__ A, const bf16_t* __restrict__ W,
              const float* __restrict__ qbias, const float* __restrict__ kbias,
              const float* __restrict__ vbias,
              bf16_t* __restrict__ Qo, bf16_t* __restrict__ Ko, bf16_t* __restrict__ Vto,
              float qscale) {
    __shared__ __align__(16) bf16_t ldsA[128 * 64];
    __shared__ __align__(16) bf16_t ldsB[128 * 64];
    const int tid = threadIdx.x;
    const int wid = tid >> 6, lane = tid & 63;
    const int m0 = blockIdx.y * 128, n0 = blockIdx.x * 128;
    const int wm = (wid & 1) * 64, wn = (wid >> 1) * 64;
    const int lm = lane & 15, quad = lane >> 4;
    const int srow = lane >> 3;
    const int scol = lane & 7;

    floatx4 acc[4][4];
    #pragma unroll
    for (int i = 0; i < 4; ++i)
        #pragma unroll
        for (int j = 0; j < 4; ++j)
            acc[i][j] = (floatx4){0.f, 0.f, 0.f, 0.f};

    for (int kt = 0; kt < S_HID; kt += 64) {
        #pragma unroll
        for (int i = 0; i < 4; ++i) {
            int slot = i * 4 + wid;
            int row = slot * 8 + srow;
            int cg = scol ^ (row & 7);
            gload_lds16(A + (size_t)(m0 + row) * S_HID + kt + cg * 8, &ldsA[slot * 512]);
            gload_lds16(W + (size_t)(n0 + row) * S_HID + kt + cg * 8, &ldsB[slot * 512]);
        }
        __syncthreads();
        #pragma unroll
        for (int k2 = 0; k2 < 2; ++k2) {
            bf16x8 af[4], bfr[4];
            #pragma unroll
            for (int i = 0; i < 4; ++i) {
                int row = wm + i * 16 + lm;
                int cc = (k2 * 4 + quad) ^ (row & 7);
                af[i] = *(const bf16x8*)&ldsA[row * 64 + cc * 8];
            }
            #pragma unroll
            for (int j = 0; j < 4; ++j) {
                int row = wn + j * 16 + lm;
                int cc = (k2 * 4 + quad) ^ (row & 7);
                bfr[j] = *(const bf16x8*)&ldsB[row * 64 + cc * 8];
            }
            #pragma unroll
            for (int i = 0; i < 4; ++i)
                #pragma unroll
                for (int j = 0; j < 4; ++j)
                    acc[i][j] = __builtin_amdgcn_mfma_f32_16x16x32_bf16(af[i], bfr[j], acc[i][j], 0, 0, 0);
        }
        __syncthreads();
    }

    const int region = n0 >> 11;   // 0=Q, 1=K, 2=V (wave-uniform)
    if (region < 2) {
        bf16_t* Ob = region ? Ko : Qo;
        const float* bias = region ? kbias : qbias;
        float scale = region ? 1.0f : qscale;
        #pragma unroll
        for (int i = 0; i < 4; ++i) {
            #pragma unroll
            for (int j = 0; j < 4; ++j) {
                int n = n0 + wn + j * 16 + lm;
                float bv = bias[n & 2047];
                int nl = n & 2047;
                int h = nl >> 7, d = nl & 127;
                #pragma unroll
                for (int r = 0; r < 4; ++r) {
                    int m = m0 + wm + i * 16 + quad * 4 + r;
                    int b = m >> 11, s = m & 2047;
                    Ob[(((size_t)(b * S_NH + h)) * S_SEQ + s) * S_HD + d] =
                        (bf16_t)((acc[i][j][r] + bv) * scale);
                }
            }
        }
    } else {
        // V^T: out[((b*16+h)*128 + d) * 2048 + s], 4 consecutive s per store
        #pragma unroll
        for (int i = 0; i < 4; ++i) {
            #pragma unroll
            for (int j = 0; j < 4; ++j) {
                int n = n0 + wn + j * 16 + lm;
                int nl = n & 2047;
                float bv = vbias[nl];
                int h = nl >> 7, d = nl & 127;
                int m = m0 + wm + i * 16 + quad * 4;
                int b = m >> 11, s = m & 2047;
                bf16x4 ov;
                #pragma unroll
                for (int r = 0; r < 4; ++r) ov[r] = (bf16_t)(acc[i][j][r] + bv);
                *(bf16x4*)&Vto[(((size_t)(b * S_NH + h)) * S_HD + d) * S_SEQ + s] = ov;
            }
        }
    }
}

// ---------------- output GEMM: out = A[4096x2048] * W[2048x2048]^T + bias (fp32) ----------------
__global__ __launch_bounds__(256, 3)
void gemm_out(const bf16_t* __restrict__ A, const bf16_t* __restrict__ W,
              const float* __restrict__ bias, float* __restrict__ out) {
    __shared__ __align__(16) bf16_t ldsA[128 * 64];
    __shared__ __align__(16) bf16_t ldsB[128 * 64];
    const int tid = threadIdx.x;
    const int wid = tid >> 6, lane = tid & 63;
    const int m0 = blockIdx.y * 128, n0 = blockIdx.x * 128;
    const int wm = (wid & 1) * 64, wn = (wid >> 1) * 64;
    const int lm = lane & 15, quad = lane >> 4;
    const int srow = lane >> 3;
    const int scol = lane & 7;

    floatx4 acc[4][4];
    #pragma unroll
    for (int i = 0; i < 4; ++i)
        #pragma unroll
        for (int j = 0; j < 4; ++j)
            acc[i][j] = (floatx4){0.f, 0.f, 0.f, 0.f};

    for (int kt = 0; kt < S_HID; kt += 64) {
        #pragma unroll
        for (int i = 0; i < 4; ++i) {
            int slot = i * 4 + wid;
            int row = slot * 8 + srow;
            int cg = scol ^ (row & 7);
            gload_lds16(A + (size_t)(m0 + row) * S_HID + kt + cg * 8, &ldsA[slot * 512]);
            gload_lds16(W + (size_t)(n0 + row) * S_HID + kt + cg * 8, &ldsB[slot * 512]);
        }
        __syncthreads();
        #pragma unroll
        for (int k2 = 0; k2 < 2; ++k2) {
            bf16x8 af[4], bfr[4];
            #pragma unroll
            for (int i = 0; i < 4; ++i) {
                int row = wm + i * 16 + lm;
                int cc = (k2 * 4 + quad) ^ (row & 7);
                af[i] = *(const bf16x8*)&ldsA[row * 64 + cc * 8];
            }
            #pragma unroll
            for (int j = 0; j < 4; ++j) {
                int row = wn + j * 16 + lm;
                int cc = (k2 * 4 + quad) ^ (row & 7);
                bfr[j] = *(const bf16x8*)&ldsB[row * 64 + cc * 8];
            }
            #pragma unroll
            for (int i = 0; i < 4; ++i)
                #pragma unroll
                for (int j = 0; j < 4; ++j)
                    acc[i][j] = __builtin_amdgcn_mfma_f32_16x16x32_bf16(af[i], bfr[j], acc[i][j], 0, 0, 0);
        }
        __syncthreads();
    }

    #pragma unroll
    for (int i = 0; i < 4; ++i) {
        #pragma unroll
        for (int j = 0; j < 4; ++j) {
            int n = n0 + wn + j * 16 + lm;
            float bv = bias[n];
            #pragma unroll
            for (int r = 0; r < 4; ++r) {
                int m = m0 + wm + i * 16 + quad * 4 + r;
                out[(size_t)m * S_HID + n] = acc[i][j][r] + bv;
            }
        }
    }
}

// Build PV B-fragment (16 keys) from packed P values via cross-half exchange.
__device__ __forceinline__ bf16x8 make_pfrag(bf16x4 lo, bf16x4 hi, int h) {
    int2 li = __builtin_bit_cast(int2, lo);
    int2 hh = __builtin_bit_cast(int2, hi);
    int2 xl, xh;
    xl.x = __shfl_xor(li.x, 32); xl.y = __shfl_xor(li.y, 32);
    xh.x = __shfl_xor(hh.x, 32); xh.y = __shfl_xor(hh.y, 32);
    int2 flo, fhi;
    flo.x = h ? xh.x : li.x;  flo.y = h ? xh.y : li.y;
    fhi.x = h ? hh.x : xl.x;  fhi.y = h ? hh.y : xl.y;
    bf16x4 a = __builtin_bit_cast(bf16x4, flo);
    bf16x4 b = __builtin_bit_cast(bf16x4, fhi);
    return __builtin_shufflevector(a, b, 0, 1, 2, 3, 4, 5, 6, 7);
}

// ---------------- flash attention (causal), S^T orientation, 64-key tiles ----------------
// Q,K: [bh][s][d] bf16 (Q pre-scaled by 1/sqrt(d)*log2e); Vt: [bh][d][s] bf16
// O: [b][s][h*128+d] bf16.
// Grid 512: bh = bx&31 (same-bh blocks share XCD), idx = bx>>5;
// qt = idx<8 ? idx : 23-idx  -> blocks bx and bx+256 (likely co-resident on a
// CU) have complementary work (36 half-tiles total). 64-key K/V tiles,
// double-buffered: LDS = 64KB -> 2 blocks/CU, 2 waves/SIMD co-scheduling.
// NOTE: with 64-key tiles under a 128-q block the causal diagonal spans the
// LAST TWO key-tiles -> mask applies for kti >= nkt-2 (was the R5 bug).
__global__ __launch_bounds__(256, 2)
void attn(const bf16_t* __restrict__ Q, const bf16_t* __restrict__ K,
          const bf16_t* __restrict__ Vt, bf16_t* __restrict__ O) {
    __shared__ __align__(16) bf16_t ldsK[2][64 * 128];    // 2 x 16KB
    __shared__ __align__(16) bf16_t ldsV[2][128 * 64];    // 2 x 16KB
    const int tid = threadIdx.x, wid = tid >> 6, lane = tid & 63;
    const int lm = lane & 15, quad = lane >> 4;           // K staging roles
    const int srow = lane >> 3, scol = lane & 7;          // V staging roles
    const int c31 = lane & 31, h = lane >> 5, r7 = lane & 7;  // compute roles
    const int bx = blockIdx.x;
    const int bh = bx & 31, idx = bx >> 5;
    const int qt = idx < 8 ? idx : 23 - idx;
    const int q0 = qt * 128;
    const int b = bh >> 4, hd = bh & 15;

    const bf16_t* Kbase = K + (size_t)bh * S_SEQ * S_HD;
    const bf16_t* Vbase = Vt + (size_t)bh * S_HD * S_SEQ;

    const int qcol = q0 + wid * 32 + c31;      // this lane's q (= S^T column)
    const int nkt = qt * 2 + 2;                // 64-key tiles

    // Q fragments (B-operand): B[k = ks*16 + h*8 + j][n = c31]
    bf16x8 qf[8];
    {
        const bf16_t* qp = Q + ((size_t)bh * S_SEQ + qcol) * S_HD + h * 8;
        #pragma unroll
        for (int ks = 0; ks < 8; ++ks) qf[ks] = *(const bf16x8*)(qp + ks * 16);
    }

    floatx16 oa[4];
    #pragma unroll
    for (int jd = 0; jd < 4; ++jd)
        #pragma unroll
        for (int e = 0; e < 16; ++e) oa[jd][e] = 0.f;
    float m_st = -1e30f, l_st = 0.f;

    // stage tile 0 into buf 0
    #pragma unroll
    for (int i = 0; i < 4; ++i) {
        int slot = i * 4 + wid;                 // 0..15
        int krow = slot * 4 + quad;             // 0..63 (K: 4 rows x 256B per KB)
        int kcg = lm ^ (krow & 7);
        gload_lds16(Kbase + (size_t)krow * S_HD + kcg * 8, &ldsK[0][slot * 512]);
        int vrow = slot * 8 + srow;             // 0..127 (V: 8 rows x 128B per KB)
        int vcg = scol ^ (vrow & 7);
        gload_lds16(Vbase + (size_t)vrow * S_SEQ + vcg * 8, &ldsV[0][slot * 512]);
    }

    int pp = 0;
    for (int kti = 0; kti < nkt; ++kti) {
        const int kt = kti * 64;
        __syncthreads();   // drains staging of tile kti

        if (kti + 1 < nkt) {   // prefetch tile kti+1 into the other buffer
            const int ktn = kt + 64;
            #pragma unroll
            for (int i = 0; i < 4; ++i) {
                int slot = i * 4 + wid;
                int krow = slot * 4 + quad;
                int kcg = lm ^ (krow & 7);
                gload_lds16(Kbase + (size_t)(ktn + krow) * S_HD + kcg * 8, &ldsK[pp ^ 1][slot * 512]);
                int vrow = slot * 8 + srow;
                int vcg = scol ^ (vrow & 7);
                gload_lds16(Vbase + (size_t)vrow * S_SEQ + ktn + vcg * 8, &ldsV[pp ^ 1][slot * 512]);
            }
        }

        // S^T = K * Q^T : A = K-frag (rows=keys, 64), B = Q-frag (cols=q)
        floatx16 sa[2];
        #pragma unroll
        for (int jr = 0; jr < 2; ++jr)
            #pragma unroll
            for (int e = 0; e < 16; ++e) sa[jr][e] = 0.f;
        #pragma unroll
        for (int ks = 0; ks < 8; ++ks) {
            #pragma unroll
            for (int jr = 0; jr < 2; ++jr) {
                int row = jr * 32 + c31;
                bf16x8 kf = *(const bf16x8*)&ldsK[pp][row * 128 + (((ks * 2 + h) ^ r7)) * 8];
                sa[jr] = __builtin_amdgcn_mfma_f32_32x32x16_bf16(kf, qf[ks], sa[jr], 0, 0, 0);
            }
        }

        // causal mask: diagonal spans the last TWO 64-key tiles of this 128-q block
        if (kti >= nkt - 2) {
            #pragma unroll
            for (int jr = 0; jr < 2; ++jr)
                #pragma unroll
                for (int rr = 0; rr < 16; ++rr) {
                    int key = kt + jr * 32 + (rr & 3) + 8 * (rr >> 2) + 4 * h;
                    if (key > qcol) sa[jr][rr] = -1e30f;
                }
        }

        // online softmax over this lane's q column (one cross-half shuffle)
        float mx = -1e30f;
        #pragma unroll
        for (int jr = 0; jr < 2; ++jr)
            #pragma unroll
            for (int rr = 0; rr < 16; ++rr) mx = fmaxf(mx, sa[jr][rr]);
        mx = fmaxf(mx, __shfl_xor(mx, 32));
        float mn = fmaxf(m_st, mx);
        float al = __builtin_amdgcn_exp2f(m_st - mn);
        m_st = mn;

        float rs = 0.f;
        bf16x8 pf[4];
        #pragma unroll
        for (int jr = 0; jr < 2; ++jr) {
            bf16x4 pk[4];
            #pragma unroll
            for (int g = 0; g < 4; ++g)
                #pragma unroll
                for (int e = 0; e < 4; ++e) {
                    float p = __builtin_amdgcn_exp2f(sa[jr][g * 4 + e] - mn);
                    rs += p;
                    pk[g][e] = (bf16_t)p;
                }
            pf[jr * 2]     = make_pfrag(pk[0], pk[1], h);
            pf[jr * 2 + 1] = make_pfrag(pk[2], pk[3], h);
        }
        rs += __shfl_xor(rs, 32);
        l_st = l_st * al + rs;
        #pragma unroll
        for (int jd = 0; jd < 4; ++jd)
            #pragma unroll
            for (int e = 0; e < 16; ++e) oa[jd][e] *= al;

        // O^T += V^T * P^T : A = V^T-frag (rows=d), B = P-frag (cols=q)
        #pragma unroll
        for (int kb = 0; kb < 4; ++kb) {
            #pragma unroll
            for (int jd = 0; jd < 4; ++jd) {
                int row = jd * 32 + c31;
                bf16x8 vf = *(const bf16x8*)&ldsV[pp][row * 64 + (((kb * 2 + h) ^ r7)) * 8];
                oa[jd] = __builtin_amdgcn_mfma_f32_32x32x16_bf16(vf, pf[kb], oa[jd], 0, 0, 0);
            }
        }
        pp ^= 1;
    }

    // epilogue: O^T C-layout: col q = qcol, row d = jd*32 + (r&3)+8*(r>>2)+4h
    float inv = 1.0f / l_st;
    bf16_t* op = O + ((size_t)b * S_SEQ + qcol) * S_HID + hd * S_HD;
    #pragma unroll
    for (int jd = 0; jd < 4; ++jd)
        #pragma unroll
        for (int g = 0; g < 4; ++g) {
            bf16x4 ov;
            #pragma unroll
            for (int e = 0; e < 4; ++e) ov[e] = (bf16_t)(oa[jd][g * 4 + e] * inv);
            *(bf16x4*)&op[jd * 32 + g * 8 + 4 * h] = ov;
        }
}

extern "C" void kernel_launch(void* const* d_in, const int* in_sizes, int n_in,
                              void* d_out, int out_size, void* d_ws, size_t ws_size,
                              hipStream_t stream) {
    const float* hs = (const float*)d_in[0];
    const float* qw = (const float*)d_in[1];
    const float* kw = (const float*)d_in[2];
    const float* vw = (const float*)d_in[3];
    const float* ow = (const float*)d_in[4];
    const float* qbias = (const float*)d_in[5];
    const float* kbias = (const float*)d_in[6];
    const float* vbias = (const float*)d_in[7];
    const float* obias = (const float*)d_in[8];

    char* ws = (char*)d_ws;
    bf16_t* Xb   = (bf16_t*)(ws + 0);           // 16 MB, reused as attention output
    bf16_t* Wqkv = (bf16_t*)(ws + 16777216);    // 32 MB stacked [q|k|v|o]
    bf16_t* Wob  = (bf16_t*)(ws + 41943040);    // last 8 MB of the stack
    bf16_t* Qb   = (bf16_t*)(ws + 50331648);    // 16 MB each
    bf16_t* Kb   = (bf16_t*)(ws + 67108864);
    bf16_t* Vtb  = (bf16_t*)(ws + 83886080);
    bf16_t* Ob   = Xb;                          // X dead after QKV GEMM

    cvt_all<<<2048, 256, 0, stream>>>(hs, qw, kw, vw, ow, Xb, Wqkv);

    // fold softmax scale 1/sqrt(128) and log2(e) into Q
    const float qscale = 0.08838834764831845f * 1.4426950408889634f;
    gemm_qkv<<<dim3(48, 32), 256, 0, stream>>>(Xb, Wqkv, qbias, kbias, vbias,
                                               Qb, Kb, Vtb, qscale);

    // 512 blocks: bh = bx&31, q-tile = (bx>>5)<8 ? idx : 23-idx
    attn<<<512, 256, 0, stream>>>(Qb, Kb, Vtb, Ob);

    gemm_out<<<dim3(16, 32), 256, 0, stream>>>(Ob, Wob, obias, (float*)d_out);
}